// Round 10
// baseline (128.884 us; speedup 1.0000x reference)
//
#include <hip/hip_runtime.h>
#include <cstdint>

// Shapes fixed by the harness:
// u, delta, z: (b=2, d=1024, l=2048) fp32; A: (d, n=16); B, C: (b, n, l); D: (d,)
constexpr int kD = 1024;
constexpr int kN = 16;
constexpr int kL = 2048;
constexpr int BLOCK = 256;       // 4 waves/block (R9 tiling)
constexpr int T  = kL / BLOCK;   // 8 timesteps per thread (two float4s)
constexpr int NW = BLOCK / 64;   // 4 waves per block
constexpr int NQ = 2;            // states per pass
constexpr int NP = kN / NQ;      // 8 passes
constexpr int PADN = NW + NW - 1;  // 3 identity rows + 4 wave rows
constexpr int RPB = 4;           // R10: rows processed SEQUENTIALLY per block
constexpr float LOG2E = 1.44269504088896340736f;

// s_waitcnt immediate (gfx9 encoding: vm[3:0]+[15:14], exp[6:4], lgkm[11:8])
constexpr unsigned WAIT_LGKM0 = 0xC07F;  // lgkmcnt(0); vmcnt/expcnt = no-wait

__device__ __forceinline__ float fast_exp2(float x) { return __builtin_amdgcn_exp2f(x); }
__device__ __forceinline__ float fast_exp(float x)  { return __builtin_amdgcn_exp2f(x * LOG2E); }
__device__ __forceinline__ float softplus_f(float x) {
  return (x > 20.0f) ? x : __logf(1.0f + fast_exp(x));
}

// DPP move with explicit 'old' (identity) — used only for the lane-exclusive
// prefix in the apply phase.
template<int CTRL, int RM>
__device__ __forceinline__ float dppf(float old_, float src) {
  union U { float f; int i; };
  U o, s, r; o.f = old_; s.f = src;
  r.i = __builtin_amdgcn_update_dpp(o.i, s.i, CTRL, RM, 0xF, false);
  return r.f;
}

__device__ __forceinline__ float readlane_f(float v, int l) {
  union U { float f; int i; };
  U a, r; a.f = v;
  r.i = __builtin_amdgcn_readlane(a.i, l);
  return r.f;
}

// Hot 64-lane scan in raw DPP asm (see prior rounds). bound_ctrl off +
// row_mask => invalid lanes DON'T WRITE dest, so in-place
//   v_fmac_f32_dpp x, x, a   (x += dpp(x)*a; boundary lanes keep x)
//   v_mul_f32_dpp  a, a, a   (a *= dpp(a);   boundary lanes keep a)
// is one masked Hillis-Steele step in 2 insts/state. NQ=2 interleave gives
// 4-inst spacing for the VALU->DPP hazard (needs 2); s_nop 1 covers entry.
#define SCAN_FM(X, A, CTRL) \
  "v_fmac_f32_dpp " X ", " X ", " A " " CTRL "\n\t" \
  "v_mul_f32_dpp "  A ", " A ", " A " " CTRL "\n\t"
#define SCAN_STEP2(CTRL) \
  SCAN_FM("%0","%2",CTRL) SCAN_FM("%1","%3",CTRL)

// One selective-scan step for element i of a state: a = exp2(spl*A);
// h = a*h + du*B; p *= a; y += C*h; cp = C*p.
#define SSTEP(i, Bc, Cc) {                         \
    float a_ = fast_exp2(spl[i] * Arn);            \
    h = fmaf(a_, h, du[i] * (Bc));                 \
    p *= a_;                                       \
    y[i] = fmaf((Cc), h, y[i]);                    \
    cp[n][i] = (Cc) * p; }

// Single-arg launch_bounds ONLY: any min-waves hint triggers a spill cascade
// (prior session notes). Keep VGPR <= 64 (8 waves/SIMD)!
// R10 = R9 (best: 256-thr/T=8/NQ=2, identity-padded fold, lgkm-only barrier)
// + GRID-STRIDE: 4 rows sequentially per block (grid 2048 -> 512).
// Rationale: OccupancyPercent is pinned at 31-39% across ALL configs
// (R2..R9) despite static caps of 8 blocks/CU — consistent with short
// (~5us) blocks never reaching steady residency (launch/drain ramp at
// every block-round). 4x longer blocks quarter the ramp events. Bonus:
// pad-fill amortized, same-b rows reuse L2-resident B/C.
// Row-to-row sAXp reuse is race-free: row r's fold-read of slot q and row
// r+1's publish to slot q are >=8 barriers apart; identity pad rows are
// never overwritten.
__global__ __launch_bounds__(BLOCK)
void selscan_kernel(const float* __restrict__ u,  const float* __restrict__ dl,
                    const float* __restrict__ A,  const float* __restrict__ Bm,
                    const float* __restrict__ Cm, const float* __restrict__ Dv,
                    const float* __restrict__ zm, float* __restrict__ out)
{
  const int tid  = threadIdx.x;
  const int lane = tid & 63;
  const int wid  = tid >> 6;            // 0..3
  const int f4   = tid * 2;             // first float4 index of this thread

  // Per-pass aggregate table with a 3-row IDENTITY PAD in front:
  // entries [q][0..NW-2]  = (a=1, x=0);  [q][NW-1 + w] = wave w's totals.
  // Wave wid's exclusive set = entries [wid .. wid+NW-2], select-free.
  // 8*7*2*8B = 896 B. Pad filled ONCE per block (identity rows are never
  // overwritten); ordered before the first fold-read by pass 0's barrier.
  __shared__ float2 sAXp[NP][PADN][NQ];
  if (tid < 64) {
    const int qq = tid >> 3, rem = tid & 7;    // qq: 0..7 = all 8 passes
    if (rem < (NW - 1) * NQ) {                 // 6 entries: 3 rows x 2 states
      sAXp[qq][rem >> 1][rem & 1] = make_float2(1.0f, 0.0f);
    }
  }

  #pragma unroll 1                      // rows sequential: live-range control
  for (int r = 0; r < RPB; ++r) {
    const int row  = blockIdx.x * RPB + r;  // b*kD + d (RPB | kD: same b)
    const int b    = row >> 10;             // kD = 1024
    const int d    = row & (kD - 1);

    const size_t roff = (size_t)row * kL;
    const float4* u4 = reinterpret_cast<const float4*>(u  + roff);
    const float4* d4 = reinterpret_cast<const float4*>(dl + roff);
    const float4* B4all = reinterpret_cast<const float4*>(Bm + (size_t)b * kN * kL);
    const float4* C4all = reinterpret_cast<const float4*>(Cm + (size_t)b * kN * kL);

    // Per-thread chunk [tid*T, tid*T+T): softplus(delta)*LOG2E and delta*u
    // in regs. u itself is NOT carried — re-loaded in the epilogue.
    float spl[T], du[T];
    {
      float4 a0 = u4[f4], a1 = u4[f4 + 1];
      float4 b0 = d4[f4], b1 = d4[f4 + 1];
      float uv[T] = {a0.x, a0.y, a0.z, a0.w, a1.x, a1.y, a1.z, a1.w};
      float dv[T] = {b0.x, b0.y, b0.z, b0.w, b1.x, b1.y, b1.z, b1.w};
      #pragma unroll
      for (int i = 0; i < T; ++i) {
        float s = softplus_f(dv[i]);
        du[i]  = s * uv[i];
        spl[i] = s * LOG2E;            // exp2 arg = spl*A == sp*LOG2E*A
      }
    }

    float y[T];
    #pragma unroll
    for (int i = 0; i < T; ++i) y[i] = 0.0f;

    #pragma unroll 1                    // passes sequential: live-range control
    for (int q = 0; q < NP; ++q) {
      // A pair for this pass: block-uniform address -> scalar-load friendly.
      const float2 av = *reinterpret_cast<const float2*>(A + (size_t)d * kN + q * NQ);
      const float4* Bq = B4all + (size_t)(q * NQ) * (kL / 4);
      const float4* Cq = C4all + (size_t)(q * NQ) * (kL / 4);

      // ---- Pass A with the cp-trick: C consumed at load time.
      // h_i = pp_i*h0 + hl_i (linearity) =>  y_i += C_i*hl_i here,
      // cp_i = C_i*pp_i saved; post-scan apply is pure register FMA.
      // Loads at point of use: compiler hoists across the unrolled n-loop as
      // register slack allows (explicit prefetch regressed R1/R3/R4/R8).
      float cp[NQ][T];
      float cA[NQ], cX[NQ];
      #pragma unroll
      for (int n = 0; n < NQ; ++n) {
        float4 b0 = Bq[n * (kL / 4) + f4];
        float4 b1 = Bq[n * (kL / 4) + f4 + 1];
        float4 c0 = Cq[n * (kL / 4) + f4];
        float4 c1 = Cq[n * (kL / 4) + f4 + 1];
        const float Arn = (n == 0) ? av.x : av.y;
        float h = 0.0f, p = 1.0f;
        SSTEP(0, b0.x, c0.x) SSTEP(1, b0.y, c0.y)
        SSTEP(2, b0.z, c0.z) SSTEP(3, b0.w, c0.w)
        SSTEP(4, b1.x, c1.x) SSTEP(5, b1.y, c1.y)
        SSTEP(6, b1.z, c1.z) SSTEP(7, b1.w, c1.w)
        cA[n] = p; cX[n] = h;
      }

      // ---- Wave-level scan on chunk aggregates — raw DPP, 2 inst/state/step.
      {
        float x0=cX[0], x1=cX[1];
        float a0_=cA[0], a1_=cA[1];
        asm("s_nop 1\n\t"
            SCAN_STEP2("row_shr:1 row_mask:0xf bank_mask:0xf")
            SCAN_STEP2("row_shr:2 row_mask:0xf bank_mask:0xf")
            SCAN_STEP2("row_shr:4 row_mask:0xf bank_mask:0xf")
            SCAN_STEP2("row_shr:8 row_mask:0xf bank_mask:0xf")
            SCAN_STEP2("row_bcast:15 row_mask:0xa bank_mask:0xf")
            SCAN_STEP2("row_bcast:31 row_mask:0xc bank_mask:0xf")
            : "+v"(x0), "+v"(x1), "+v"(a0_), "+v"(a1_));
        cX[0]=x0; cX[1]=x1;
        cA[0]=a0_; cA[1]=a1_;
      }

      // ---- Publish wave totals (lane 63 holds them), ONE barrier (raw:
      // lgkm drain only — no vmcnt drain, in-flight globals keep flying).
      if (lane == 63) {
        #pragma unroll
        for (int n = 0; n < NQ; ++n)
          sAXp[q][(NW - 1) + wid][n] = make_float2(cA[n], cX[n]);
      }
      __builtin_amdgcn_s_waitcnt(WAIT_LGKM0);
      __builtin_amdgcn_s_barrier();

      // ---- Parallel exclusive fold, select-free: read the 3 entries at
      // [wid+k] (k=0..2) — identity pad makes out-of-range waves no-ops.
      // ex = fold oldest-first: ex = a*ex + x over waves 0..wid-1.
      float ex = 0.0f;                   // lane n<2: exclusive x-prefix, state n
      {
        const int n = lane & (NQ - 1);
        #pragma unroll
        for (int k = 0; k < NW - 1; ++k) {
          float2 s = sAXp[q][wid + k][n];
          ex = s.x * ex + s.y;
        }
      }

      // ---- Apply: y_i += cp_i * h0  (pure FMA; exn broadcast via readlane)
      #pragma unroll
      for (int n = 0; n < NQ; ++n) {
        float al = dppf<0x138,0xF>(1.0f, cA[n]);   // lane-exclusive prefix
        float xl = dppf<0x138,0xF>(0.0f, cX[n]);
        float exn = readlane_f(ex, n);             // scalar: wave-exclusive x
        float h0 = al * exn + xl;                  // state entering this chunk
        #pragma unroll
        for (int i = 0; i < T; ++i) y[i] += cp[n][i] * h0;
      }
      // no end-of-pass sync: each pass uses its own sAXp buffer; next row's
      // publish to slot q is >=8 barriers after this fold-read.
    }

    // ---- Epilogue: + u*D, * silu(z), store  (u re-loaded here)
    const float Dd = Dv[d];
    const float4* z4 = reinterpret_cast<const float4*>(zm + roff);
    float4 z0 = z4[f4], z1 = z4[f4 + 1];
    float4 ua = u4[f4], ub = u4[f4 + 1];
    float zv[T] = {z0.x, z0.y, z0.z, z0.w, z1.x, z1.y, z1.z, z1.w};
    float uv[T] = {ua.x, ua.y, ua.z, ua.w, ub.x, ub.y, ub.z, ub.w};
    float ov[T];
    #pragma unroll
    for (int i = 0; i < T; ++i) {
      float yy  = y[i] + uv[i] * Dd;
      float sig = 1.0f / (1.0f + fast_exp(-zv[i]));
      ov[i] = yy * zv[i] * sig;
    }
    float4* o4 = reinterpret_cast<float4*>(out + roff);
    o4[f4]     = make_float4(ov[0], ov[1], ov[2], ov[3]);
    o4[f4 + 1] = make_float4(ov[4], ov[5], ov[6], ov[7]);
  }
}

extern "C" void kernel_launch(void* const* d_in, const int* in_sizes, int n_in,
                              void* d_out, int out_size, void* d_ws, size_t ws_size,
                              hipStream_t stream)
{
  const float* u  = (const float*)d_in[0];
  const float* dl = (const float*)d_in[1];
  const float* A  = (const float*)d_in[2];
  const float* Bm = (const float*)d_in[3];
  const float* Cm = (const float*)d_in[4];
  const float* Dv = (const float*)d_in[5];
  const float* zm = (const float*)d_in[6];
  float* out = (float*)d_out;
  const int rows = in_sizes[0] / kL;   // b*d = 2048
  selscan_kernel<<<rows / RPB, BLOCK, 0, stream>>>(u, dl, A, Bm, Cm, Dv, zm, out);
}

// Round 11
// 118.904 us; speedup vs baseline: 1.0839x; 1.0839x over previous
//
#include <hip/hip_runtime.h>
#include <cstdint>

// Shapes fixed by the harness:
// u, delta, z: (b=2, d=1024, l=2048) fp32; A: (d, n=16); B, C: (b, n, l); D: (d,)
constexpr int kD = 1024;
constexpr int kN = 16;
constexpr int kL = 2048;
constexpr int BLOCK = 256;       // best config (R9): half waves, 2x elems/wave
constexpr int T  = kL / BLOCK;   // 8 timesteps per thread (two float4s)
constexpr int NW = BLOCK / 64;   // 4 waves per block
constexpr int NQ = 2;            // states per pass
constexpr int NP = kN / NQ;      // 8 passes
constexpr int PADN = NW + NW - 1;  // 3 identity rows + 4 wave rows
constexpr float LOG2E = 1.44269504088896340736f;

// s_waitcnt immediate (gfx9 encoding: vm[3:0]+[15:14], exp[6:4], lgkm[11:8])
constexpr unsigned WAIT_LGKM0 = 0xC07F;  // lgkmcnt(0); vmcnt/expcnt = no-wait

__device__ __forceinline__ float fast_exp2(float x) { return __builtin_amdgcn_exp2f(x); }
__device__ __forceinline__ float fast_exp(float x)  { return __builtin_amdgcn_exp2f(x * LOG2E); }
__device__ __forceinline__ float softplus_f(float x) {
  return (x > 20.0f) ? x : __logf(1.0f + fast_exp(x));
}

// DPP move with explicit 'old' (identity) — used only for the lane-exclusive
// prefix in the apply phase.
template<int CTRL, int RM>
__device__ __forceinline__ float dppf(float old_, float src) {
  union U { float f; int i; };
  U o, s, r; o.f = old_; s.f = src;
  r.i = __builtin_amdgcn_update_dpp(o.i, s.i, CTRL, RM, 0xF, false);
  return r.f;
}

__device__ __forceinline__ float readlane_f(float v, int l) {
  union U { float f; int i; };
  U a, r; a.f = v;
  r.i = __builtin_amdgcn_readlane(a.i, l);
  return r.f;
}

// Hot 64-lane scan in raw DPP asm. bound_ctrl off + row_mask => invalid
// lanes DON'T WRITE dest, so in-place
//   v_fmac_f32_dpp x, x, a   (x += dpp(x)*a; boundary lanes keep x)
//   v_mul_f32_dpp  a, a, a   (a *= dpp(a);   boundary lanes keep a)
// is one masked Hillis-Steele step in 2 insts/state. NQ=2 interleave gives
// 4-inst spacing for the VALU->DPP hazard (needs 2); s_nop 1 covers entry.
#define SCAN_FM(X, A, CTRL) \
  "v_fmac_f32_dpp " X ", " X ", " A " " CTRL "\n\t" \
  "v_mul_f32_dpp "  A ", " A ", " A " " CTRL "\n\t"
#define SCAN_STEP2(CTRL) \
  SCAN_FM("%0","%2",CTRL) SCAN_FM("%1","%3",CTRL)

// One selective-scan step for element i of a state: a = exp2(spl*A);
// h = a*h + du*B; p *= a; y += C*h; cp = C*p.
#define SSTEP(i, Bc, Cc) {                         \
    float a_ = fast_exp2(spl[i] * Arn);            \
    h = fmaf(a_, h, du[i] * (Bc));                 \
    p *= a_;                                       \
    y[i] = fmaf((Cc), h, y[i]);                    \
    cp[n][i] = (Cc) * p; }

// Single-arg launch_bounds ONLY: any min-waves hint triggers a spill cascade
// (prior session notes). Keep VGPR <= 64 (8 waves/SIMD)!
//
// R11 == R9, the verified best (worst-dispatch ~41.6us). Session ledger:
//   WON:  occupancy via <=64-VGPR cliff (R2, -24%); select-free fold +
//         lgkm-only barrier (R6, -11%); T=8/NQ=2 wave-fixed-work halving
//         (R9, -3%).
//   NULL: latency scheduling x4 (R1/R3/R4/R8); directional sync (R7).
//   REGRESSED: wider sync (R5); grid-stride TLP cut (R10).
// Structural constraint: per-(elem,state) chain exp2+4fma/mul ~16 issue-cy
// -> ~3000 cy/wave; stall-free floor ~25-28us; measured ~41.6us at
// VALUBusy 48% / HBM 13% — latency-bound residual that resisted six
// targeted removals. Further gain needs cheaper recurrence algebra (all
// explored variants >= equal VALU or VGPR-infeasible) or HW-level behavior
// outside source control.
__global__ __launch_bounds__(BLOCK)
void selscan_kernel(const float* __restrict__ u,  const float* __restrict__ dl,
                    const float* __restrict__ A,  const float* __restrict__ Bm,
                    const float* __restrict__ Cm, const float* __restrict__ Dv,
                    const float* __restrict__ zm, float* __restrict__ out)
{
  const int row  = blockIdx.x;          // b*kD + d
  const int b    = row >> 10;           // kD = 1024
  const int d    = row & (kD - 1);
  const int tid  = threadIdx.x;
  const int lane = tid & 63;
  const int wid  = tid >> 6;            // 0..3
  const int f4   = tid * 2;             // first float4 index of this thread

  const size_t roff = (size_t)row * kL;
  const float4* u4 = reinterpret_cast<const float4*>(u  + roff);
  const float4* d4 = reinterpret_cast<const float4*>(dl + roff);
  const float4* B4all = reinterpret_cast<const float4*>(Bm + (size_t)b * kN * kL);
  const float4* C4all = reinterpret_cast<const float4*>(Cm + (size_t)b * kN * kL);

  // Per-pass aggregate table with a 3-row IDENTITY PAD in front:
  // entries [q][0..NW-2]  = (a=1, x=0);  [q][NW-1 + w] = wave w's totals.
  // Wave wid's exclusive set = entries [wid .. wid+NW-2], select-free.
  // 8*7*2*8B = 896 B. Pad fill ordered before any fold-read by pass 0's
  // barrier.
  __shared__ float2 sAXp[NP][PADN][NQ];
  if (tid < 64) {
    const int qq = tid >> 3, rem = tid & 7;    // qq: 0..7 = all 8 passes
    if (rem < (NW - 1) * NQ) {                 // 6 entries: 3 rows x 2 states
      sAXp[qq][rem >> 1][rem & 1] = make_float2(1.0f, 0.0f);
    }
  }

  // Per-thread chunk [tid*T, tid*T+T): softplus(delta)*LOG2E and delta*u in
  // regs. u itself is NOT carried — re-loaded in the epilogue.
  float spl[T], du[T];
  {
    float4 a0 = u4[f4], a1 = u4[f4 + 1];
    float4 b0 = d4[f4], b1 = d4[f4 + 1];
    float uv[T] = {a0.x, a0.y, a0.z, a0.w, a1.x, a1.y, a1.z, a1.w};
    float dv[T] = {b0.x, b0.y, b0.z, b0.w, b1.x, b1.y, b1.z, b1.w};
    #pragma unroll
    for (int i = 0; i < T; ++i) {
      float s = softplus_f(dv[i]);
      du[i]  = s * uv[i];
      spl[i] = s * LOG2E;              // exp2 arg = spl*A == sp*LOG2E*A
    }
  }

  float y[T];
  #pragma unroll
  for (int i = 0; i < T; ++i) y[i] = 0.0f;

  #pragma unroll 1                      // passes sequential: live-range control
  for (int q = 0; q < NP; ++q) {
    // A pair for this pass: block-uniform address -> scalar-load friendly.
    const float2 av = *reinterpret_cast<const float2*>(A + (size_t)d * kN + q * NQ);
    const float4* Bq = B4all + (size_t)(q * NQ) * (kL / 4);
    const float4* Cq = C4all + (size_t)(q * NQ) * (kL / 4);

    // ---- Pass A with the cp-trick: C consumed at load time.
    // h_i = pp_i*h0 + hl_i (linearity) =>  y_i += C_i*hl_i here,
    // cp_i = C_i*pp_i saved; post-scan apply is pure register FMA.
    // Loads at point of use: compiler hoists across the unrolled n-loop as
    // register slack allows (explicit prefetch regressed R1/R3/R4/R8).
    float cp[NQ][T];
    float cA[NQ], cX[NQ];
    #pragma unroll
    for (int n = 0; n < NQ; ++n) {
      float4 b0 = Bq[n * (kL / 4) + f4];
      float4 b1 = Bq[n * (kL / 4) + f4 + 1];
      float4 c0 = Cq[n * (kL / 4) + f4];
      float4 c1 = Cq[n * (kL / 4) + f4 + 1];
      const float Arn = (n == 0) ? av.x : av.y;
      float h = 0.0f, p = 1.0f;
      SSTEP(0, b0.x, c0.x) SSTEP(1, b0.y, c0.y)
      SSTEP(2, b0.z, c0.z) SSTEP(3, b0.w, c0.w)
      SSTEP(4, b1.x, c1.x) SSTEP(5, b1.y, c1.y)
      SSTEP(6, b1.z, c1.z) SSTEP(7, b1.w, c1.w)
      cA[n] = p; cX[n] = h;
    }

    // ---- Wave-level scan on chunk aggregates — raw DPP, 2 inst/state/step.
    {
      float x0=cX[0], x1=cX[1];
      float a0_=cA[0], a1_=cA[1];
      asm("s_nop 1\n\t"
          SCAN_STEP2("row_shr:1 row_mask:0xf bank_mask:0xf")
          SCAN_STEP2("row_shr:2 row_mask:0xf bank_mask:0xf")
          SCAN_STEP2("row_shr:4 row_mask:0xf bank_mask:0xf")
          SCAN_STEP2("row_shr:8 row_mask:0xf bank_mask:0xf")
          SCAN_STEP2("row_bcast:15 row_mask:0xa bank_mask:0xf")
          SCAN_STEP2("row_bcast:31 row_mask:0xc bank_mask:0xf")
          : "+v"(x0), "+v"(x1), "+v"(a0_), "+v"(a1_));
      cX[0]=x0; cX[1]=x1;
      cA[0]=a0_; cA[1]=a1_;
    }

    // ---- Publish wave totals (lane 63 holds them), ONE barrier (raw: lgkm
    // drain only — no vmcnt drain, so in-flight globals keep flying).
    if (lane == 63) {
      #pragma unroll
      for (int n = 0; n < NQ; ++n)
        sAXp[q][(NW - 1) + wid][n] = make_float2(cA[n], cX[n]);
    }
    __builtin_amdgcn_s_waitcnt(WAIT_LGKM0);
    __builtin_amdgcn_s_barrier();

    // ---- Parallel exclusive fold, select-free: read the 3 entries at
    // [wid+k] (k=0..2) — identity pad makes out-of-range waves no-ops.
    // ex = fold oldest-first: ex = a*ex + x over waves 0..wid-1.
    float ex = 0.0f;                     // lane n<2: exclusive x-prefix, state n
    {
      const int n = lane & (NQ - 1);
      #pragma unroll
      for (int k = 0; k < NW - 1; ++k) {
        float2 s = sAXp[q][wid + k][n];
        ex = s.x * ex + s.y;
      }
    }

    // ---- Apply: y_i += cp_i * h0   (pure FMA; exn broadcast via readlane)
    #pragma unroll
    for (int n = 0; n < NQ; ++n) {
      float al = dppf<0x138,0xF>(1.0f, cA[n]);   // lane-exclusive prefix
      float xl = dppf<0x138,0xF>(0.0f, cX[n]);
      float exn = readlane_f(ex, n);             // scalar: wave-exclusive x
      float h0 = al * exn + xl;                  // state entering this chunk
      #pragma unroll
      for (int i = 0; i < T; ++i) y[i] += cp[n][i] * h0;
    }
    // no end-of-pass sync: each pass uses its own sAXp buffer
  }

  // ---- Epilogue: + u*D, * silu(z), store  (u re-loaded here)
  const float Dd = Dv[d];
  const float4* z4 = reinterpret_cast<const float4*>(zm + roff);
  float4 z0 = z4[f4], z1 = z4[f4 + 1];
  float4 ua = u4[f4], ub = u4[f4 + 1];
  float zv[T] = {z0.x, z0.y, z0.z, z0.w, z1.x, z1.y, z1.z, z1.w};
  float uv[T] = {ua.x, ua.y, ua.z, ua.w, ub.x, ub.y, ub.z, ub.w};
  float ov[T];
  #pragma unroll
  for (int i = 0; i < T; ++i) {
    float yy  = y[i] + uv[i] * Dd;
    float sig = 1.0f / (1.0f + fast_exp(-zv[i]));
    ov[i] = yy * zv[i] * sig;
  }
  float4* o4 = reinterpret_cast<float4*>(out + roff);
  o4[f4]     = make_float4(ov[0], ov[1], ov[2], ov[3]);
  o4[f4 + 1] = make_float4(ov[4], ov[5], ov[6], ov[7]);
}

extern "C" void kernel_launch(void* const* d_in, const int* in_sizes, int n_in,
                              void* d_out, int out_size, void* d_ws, size_t ws_size,
                              hipStream_t stream)
{
  const float* u  = (const float*)d_in[0];
  const float* dl = (const float*)d_in[1];
  const float* A  = (const float*)d_in[2];
  const float* Bm = (const float*)d_in[3];
  const float* Cm = (const float*)d_in[4];
  const float* Dv = (const float*)d_in[5];
  const float* zm = (const float*)d_in[6];
  float* out = (float*)d_out;
  const int rows = in_sizes[0] / kL;   // b*d = 2048
  selscan_kernel<<<rows, BLOCK, 0, stream>>>(u, dl, A, Bm, Cm, Dv, zm, out);
}